// Round 1
// baseline (25163.457 us; speedup 1.0000x reference)
//
#include <hip/hip_runtime.h>
#include <hip/hip_bf16.h>
#include <math.h>

#define BB 256
#define SS 256
#define DIN 300
#define D2 300
#define HH 512

__device__ __forceinline__ float sigf(float x) { return 1.0f / (1.0f + expf(-x)); }

// ---------------------------------------------------------------------------
// Generic 32x64 tiled fp32 GEMM, double-buffered LDS, fused epilogue.
// mode 0: C = tanh(A@B + aux[col])          (aux = bias vector)
// mode 1: C = 2*sigmoid(A@B) * aux[r*auxStride + col]
// M (rows) implicit from gridDim.y*32, must divide evenly. N guarded.
// ---------------------------------------------------------------------------
__global__ __launch_bounds__(256) void gemm_tile(
    const float* __restrict__ A, int lda,
    const float* __restrict__ B, int ldb,
    int K, int N,
    float* __restrict__ C, int ldc,
    const float* __restrict__ aux, int auxStride, int mode)
{
    __shared__ float As[2][16][34];   // [kk][r], stride 34 (even, conflict-free)
    __shared__ float Bs[2][16][64];   // [kk][c]
    const int tid = threadIdx.x;
    const int m0 = blockIdx.y * 32;
    const int n0 = blockIdx.x * 64;
    const int tx = tid & 15;          // 16 col groups * 4 cols
    const int ty = tid >> 4;          // 16 row groups * 2 rows
    float acc[2][4] = {{0.f,0.f,0.f,0.f},{0.f,0.f,0.f,0.f}};
    const int NC = (K + 15) >> 4;

    float ra0, ra1, rb[4];
    auto load_regs = [&](int c) {
        const int k0 = c << 4;
        int e = tid, kk = e & 15, r = e >> 4;
        ra0 = (k0 + kk < K) ? A[(m0 + r) * lda + k0 + kk] : 0.f;
        e = tid + 256; kk = e & 15; r = e >> 4;
        ra1 = (k0 + kk < K) ? A[(m0 + r) * lda + k0 + kk] : 0.f;
#pragma unroll
        for (int i = 0; i < 4; ++i) {
            int e2 = tid + (i << 8);
            int kk2 = e2 >> 6, cc = e2 & 63;
            rb[i] = (k0 + kk2 < K && n0 + cc < N) ? B[(k0 + kk2) * ldb + n0 + cc] : 0.f;
        }
    };
    auto store_lds = [&](int buf) {
        int e = tid; As[buf][e & 15][e >> 4] = ra0;
        e = tid + 256; As[buf][e & 15][e >> 4] = ra1;
#pragma unroll
        for (int i = 0; i < 4; ++i) {
            int e2 = tid + (i << 8);
            Bs[buf][e2 >> 6][e2 & 63] = rb[i];
        }
    };

    load_regs(0); store_lds(0);
    for (int c = 0; c < NC; ++c) {
        __syncthreads();
        if (c + 1 < NC) load_regs(c + 1);
        const int buf = c & 1;
#pragma unroll
        for (int kk = 0; kk < 16; ++kk) {
            float2 a = *(const float2*)&As[buf][kk][ty * 2];
            float4 b = *(const float4*)&Bs[buf][kk][tx * 4];
            acc[0][0] += a.x * b.x; acc[0][1] += a.x * b.y;
            acc[0][2] += a.x * b.z; acc[0][3] += a.x * b.w;
            acc[1][0] += a.y * b.x; acc[1][1] += a.y * b.y;
            acc[1][2] += a.y * b.z; acc[1][3] += a.y * b.w;
        }
        if (c + 1 < NC) store_lds((c + 1) & 1);
    }

#pragma unroll
    for (int j = 0; j < 2; ++j) {
        const int r = m0 + ty * 2 + j;
#pragma unroll
        for (int i = 0; i < 4; ++i) {
            const int ccol = n0 + tx * 4 + i;
            if (ccol < N) {
                float v = acc[j][i];
                float outv;
                if (mode == 0) {
                    outv = tanhf(v + aux[ccol]);
                } else {
                    outv = 2.0f * sigf(v) * aux[(size_t)r * auxStride + ccol];
                }
                C[(size_t)r * ldc + ccol] = outv;
            }
        }
    }
}

// ---------------------------------------------------------------------------
// Gates GEMM + LSTM cell update, fused. Tile: 16 rows x 32 h x 4 gate segs.
// gates = xt2 @ Wih + ht2 @ Whh + bih + bhh ; then cell update, writes
// ct, ht (fp32) and hseq[:, t, :] (bf16).
// ---------------------------------------------------------------------------
__global__ __launch_bounds__(256) void gates_kernel(
    const float* __restrict__ xt2, const float* __restrict__ ht2,
    const float* __restrict__ Wih, const float* __restrict__ Whh,
    const float* __restrict__ bih, const float* __restrict__ bhh,
    float* __restrict__ ct, float* __restrict__ ht,
    __hip_bfloat16* __restrict__ hseq, int t)
{
    __shared__ float As[2][16][18];     // [kk][r], stride 18
    __shared__ float Bs[2][16][128];    // [kk][hx*4 + seg]
    const int tid = threadIdx.x;
    const int h0 = blockIdx.x * 32;
    const int b0 = blockIdx.y * 16;
    const int hx = tid & 31;
    const int rp = tid >> 5;            // 0..7 -> rows 2*rp, 2*rp+1
    float acc[2][4] = {{0.f,0.f,0.f,0.f},{0.f,0.f,0.f,0.f}};

    const int NC1 = (D2 + 15) >> 4;     // 19
    const int NC2 = (HH + 15) >> 4;     // 32
    const int NC = NC1 + NC2;           // 51

    float ra, rb[8];
    auto load_regs = [&](int c) {
        const float* Ap; const float* W; int lda, K, k0;
        if (c < NC1) { Ap = xt2; W = Wih; lda = D2; K = D2; k0 = c << 4; }
        else         { Ap = ht2; W = Whh; lda = HH; K = HH; k0 = (c - NC1) << 4; }
        int e = tid, kk = e & 15, r = e >> 4;
        ra = (k0 + kk < K) ? Ap[(b0 + r) * lda + k0 + kk] : 0.f;
#pragma unroll
        for (int i = 0; i < 8; ++i) {
            int e2 = tid + (i << 8);
            int kk2 = e2 >> 7, cc = e2 & 127, s = cc >> 5, hh = cc & 31;
            rb[i] = (k0 + kk2 < K) ? W[(size_t)(k0 + kk2) * 2048 + s * 512 + h0 + hh] : 0.f;
        }
    };
    auto store_lds = [&](int buf) {
        int e = tid;
        As[buf][e & 15][e >> 4] = ra;
#pragma unroll
        for (int i = 0; i < 8; ++i) {
            int e2 = tid + (i << 8);
            int kk2 = e2 >> 7, cc = e2 & 127, s = cc >> 5, hh = cc & 31;
            Bs[buf][kk2][hh * 4 + s] = rb[i];
        }
    };

    load_regs(0); store_lds(0);
    for (int c = 0; c < NC; ++c) {
        __syncthreads();
        if (c + 1 < NC) load_regs(c + 1);
        const int buf = c & 1;
#pragma unroll
        for (int kk = 0; kk < 16; ++kk) {
            float2 a = *(const float2*)&As[buf][kk][rp * 2];
            float4 b = *(const float4*)&Bs[buf][kk][hx * 4];
            acc[0][0] += a.x * b.x; acc[0][1] += a.x * b.y;
            acc[0][2] += a.x * b.z; acc[0][3] += a.x * b.w;
            acc[1][0] += a.y * b.x; acc[1][1] += a.y * b.y;
            acc[1][2] += a.y * b.z; acc[1][3] += a.y * b.w;
        }
        if (c + 1 < NC) store_lds((c + 1) & 1);
    }

    const int h = h0 + hx;
    const float bi0 = bih[h] + bhh[h];
    const float bi1 = bih[512 + h] + bhh[512 + h];
    const float bi2 = bih[1024 + h] + bhh[1024 + h];
    const float bi3 = bih[1536 + h] + bhh[1536 + h];
#pragma unroll
    for (int j = 0; j < 2; ++j) {
        const int r = b0 + rp * 2 + j;
        const float ig = acc[j][0] + bi0;
        const float fg = acc[j][1] + bi1;
        const float gg = acc[j][2] + bi2;
        const float og = acc[j][3] + bi3;
        const size_t idx = (size_t)r * 512 + h;
        const float c_old = ct[idx];
        const float cn = sigf(fg) * c_old + sigf(ig) * tanhf(gg);
        const float hn = sigf(og) * tanhf(cn);
        ct[idx] = cn;
        ht[idx] = hn;
        hseq[((size_t)r * SS + t) * 512 + h] = __float2bfloat16(hn);
    }
}

// ---------------------------------------------------------------------------
// Conv + relu + maxpool over time. One WG per batch row. hseq is bf16.
// 16 phases of 16 t0 each; stage (16+4)x512 rows in LDS (stride 516).
// ---------------------------------------------------------------------------
__global__ __launch_bounds__(256) void conv_kernel(
    const __hip_bfloat16* __restrict__ hseq,
    const float* __restrict__ w3, const float* __restrict__ cb3,
    const float* __restrict__ w4, const float* __restrict__ cb4,
    const float* __restrict__ w5, const float* __restrict__ cb5,
    float* __restrict__ feats)
{
    __shared__ float sh[20 * 516];
    __shared__ float part[16 * 16 * 9];
    __shared__ int rmax[9];
    const int b = blockIdx.x;
    const int tid = threadIdx.x;
    if (tid < 9) rmax[tid] = 0;   // relu outputs >= 0 so 0.0f bits are a valid identity
    const int wv = tid >> 6, lane = tid & 63;
    const int t0l = lane >> 2, hs = lane & 3;

    for (int p = 0; p < 16; ++p) {
        __syncthreads();
        // stage rows p*16 .. p*16+19 (zero past S)
#pragma unroll
        for (int i = 0; i < 5; ++i) {
            int e = tid + (i << 8);         // 0..1279
            int row = e >> 6, q = e & 63;
            int tg = p * 16 + row;
            float v[8];
            if (tg < SS) {
                uint4 u = *(const uint4*)(hseq + (((size_t)b * SS + tg) << 9) + (q << 3));
                v[0] = __uint_as_float(u.x << 16); v[1] = __uint_as_float(u.x & 0xffff0000u);
                v[2] = __uint_as_float(u.y << 16); v[3] = __uint_as_float(u.y & 0xffff0000u);
                v[4] = __uint_as_float(u.z << 16); v[5] = __uint_as_float(u.z & 0xffff0000u);
                v[6] = __uint_as_float(u.w << 16); v[7] = __uint_as_float(u.w & 0xffff0000u);
            } else {
#pragma unroll
                for (int j = 0; j < 8; ++j) v[j] = 0.f;
            }
#pragma unroll
            for (int j = 0; j < 8; ++j) sh[row * 516 + q * 8 + j] = v[j];
        }
        __syncthreads();

        float acc[9];
#pragma unroll
        for (int j = 0; j < 9; ++j) acc[j] = 0.f;
        for (int k = 0; k < 32; ++k) {
            const int h = (wv << 7) + (k << 2) + hs;
            const float v0 = sh[(t0l + 0) * 516 + h];
            const float v1 = sh[(t0l + 1) * 516 + h];
            const float v2 = sh[(t0l + 2) * 516 + h];
            const float v3 = sh[(t0l + 3) * 516 + h];
            const float v4 = sh[(t0l + 4) * 516 + h];
#pragma unroll
            for (int f = 0; f < 3; ++f) {
                acc[f]     += v0 * w3[(f * 3 + 0) * 512 + h] + v1 * w3[(f * 3 + 1) * 512 + h]
                            + v2 * w3[(f * 3 + 2) * 512 + h];
                acc[3 + f] += v0 * w4[(f * 4 + 0) * 512 + h] + v1 * w4[(f * 4 + 1) * 512 + h]
                            + v2 * w4[(f * 4 + 2) * 512 + h] + v3 * w4[(f * 4 + 3) * 512 + h];
                acc[6 + f] += v0 * w5[(f * 5 + 0) * 512 + h] + v1 * w5[(f * 5 + 1) * 512 + h]
                            + v2 * w5[(f * 5 + 2) * 512 + h] + v3 * w5[(f * 5 + 3) * 512 + h]
                            + v4 * w5[(f * 5 + 4) * 512 + h];
            }
        }
        const int pi = (wv << 2) + hs;   // 0..15
#pragma unroll
        for (int j = 0; j < 9; ++j) part[(pi * 16 + t0l) * 9 + j] = acc[j];
        __syncthreads();
        if (tid < 144) {
            const int tl = tid / 9, j = tid % 9;
            float s = 0.f;
#pragma unroll
            for (int pp = 0; pp < 16; ++pp) s += part[(pp * 16 + tl) * 9 + j];
            const int fsz = j < 3 ? 3 : (j < 6 ? 4 : 5);
            const int t0 = p * 16 + tl;
            if (t0 <= SS - fsz) {
                const float bias = j < 3 ? cb3[j] : (j < 6 ? cb4[j - 3] : cb5[j - 6]);
                float v = s + bias;
                v = v > 0.f ? v : 0.f;
                atomicMax(&rmax[j], __float_as_int(v));
            }
        }
    }
    __syncthreads();
    if (tid < 9) feats[b * 9 + tid] = __int_as_float(rmax[tid]);
}

__global__ void final_kernel(const float* __restrict__ feats,
                             const float* __restrict__ lin_w,
                             const float* __restrict__ lin_b,
                             float* __restrict__ out)
{
    const int b = threadIdx.x;
    float o0 = lin_b[0], o1 = lin_b[1];
#pragma unroll
    for (int j = 0; j < 9; ++j) {
        const float f = feats[b * 9 + j];
        o0 += f * lin_w[j * 2 + 0];
        o1 += f * lin_w[j * 2 + 1];
    }
    out[b * 2 + 0] = o0;
    out[b * 2 + 1] = o1;
}

extern "C" void kernel_launch(void* const* d_in, const int* in_sizes, int n_in,
                              void* d_out, int out_size, void* d_ws, size_t ws_size,
                              hipStream_t stream) {
    const float* x    = (const float*)d_in[0];
    const float* W_in = (const float*)d_in[1];
    const float* b_in = (const float*)d_in[2];
    const float* Wih  = (const float*)d_in[3];
    const float* Whh  = (const float*)d_in[4];
    const float* bih  = (const float*)d_in[5];
    const float* bhh  = (const float*)d_in[6];
    const float* Q    = (const float*)d_in[7];
    const float* R    = (const float*)d_in[8];
    const float* lin_w = (const float*)d_in[9];
    const float* lin_b = (const float*)d_in[10];
    const float* w3 = (const float*)d_in[11];
    const float* cb3 = (const float*)d_in[12];
    const float* w4 = (const float*)d_in[13];
    const float* cb4 = (const float*)d_in[14];
    const float* w5 = (const float*)d_in[15];
    const float* cb5 = (const float*)d_in[16];

    float* ws = (float*)d_ws;
    float* xp   = ws;                              // 65536*300
    float* xt2  = xp + (size_t)BB * SS * D2;       // 256*300
    float* ht   = xt2 + BB * D2;                   // 256*512
    float* ht2  = ht + BB * HH;                    // 256*512
    float* ct   = ht2 + BB * HH;                   // 256*512
    float* feats = ct + BB * HH;                   // 256*9
    __hip_bfloat16* hseq = (__hip_bfloat16*)(feats + BB * 9);  // 256*256*512 bf16

    // zero ht, ht2, ct (contiguous)
    hipMemsetAsync(ht, 0, (size_t)3 * BB * HH * sizeof(float), stream);

    // xp = tanh(x @ W_in + b_in):  M=65536, K=300, N=300
    gemm_tile<<<dim3(5, 2048), 256, 0, stream>>>(x, DIN, W_in, D2, DIN, D2,
                                                 xp, D2, b_in, 0, 0);

    for (int t = 0; t < SS; ++t) {
        // mog1: xt2 = 2*sig(ht @ Q) * xp[:, t, :]   M=256 K=512 N=300
        gemm_tile<<<dim3(5, 8), 256, 0, stream>>>(ht, HH, Q, D2, HH, D2,
                                                  xt2, D2, xp + (size_t)t * D2, SS * D2, 1);
        // mog2: ht2 = 2*sig(xt2 @ R) * ht           M=256 K=300 N=512
        gemm_tile<<<dim3(8, 8), 256, 0, stream>>>(xt2, D2, R, HH, D2, HH,
                                                  ht2, HH, ht, HH, 1);
        // gates + cell update
        gates_kernel<<<dim3(16, 16), 256, 0, stream>>>(xt2, ht2, Wih, Whh, bih, bhh,
                                                       ct, ht, hseq, t);
    }

    conv_kernel<<<dim3(256), 256, 0, stream>>>(hseq, w3, cb3, w4, cb4, w5, cb5, feats);
    final_kernel<<<dim3(1), 256, 0, stream>>>(feats, lin_w, lin_b, (float*)d_out);
}